// Round 7
// baseline (173.701 us; speedup 1.0000x reference)
//
#include <hip/hip_runtime.h>
#include <hip/hip_bf16.h>

// Chunked simple-GLA forward, B=2 H=32 T=4096 K=V=128, BT=64.
// Two-kernel T-split (P=4 segments):
//   gla_pre : 192 blocks (64 bh x 3 subsegs) compute per-1024-token KV sums
//             + gate totals into d_ws (pure weighted sums, fully parallel).
//   gla_main: 256 blocks (64 bh x 4 segments), FULL V=128 per block,
//             16 sequential chunks, entry state combined from ws.
// Falls back to the R6 single-kernel (gla_fused) if ws is too small.

#define BT 64
#define KD 128
#define VD 128
#define VSG 32          // legacy kernel's v-segment width
#define NCHUNK 64       // legacy
#define SEGC 16         // chunks per segment (new)
#define TLEN 4096
#define SCALE 0.08838834764831845f   // 128^-0.5

#define QSTR 136
#define SHSTR 72
#define SVSTR 136
#define VTSTR 72

#define KV_PER 16384                    // floats per KV block (128x128)
#define KV_TOT (64 * 3 * KV_PER)
#define GS_OFF KV_TOT
#define WS_NEED ((size_t)(KV_TOT + 192) * 4)

typedef __bf16 bf16;
typedef __bf16 bf16x8 __attribute__((ext_vector_type(8)));
typedef __bf16 bf16x4 __attribute__((ext_vector_type(4)));
typedef float f32x4 __attribute__((ext_vector_type(4)));

#define MFMA __builtin_amdgcn_mfma_f32_16x16x32_bf16
#define LGKM_BARRIER() do { asm volatile("s_waitcnt lgkmcnt(0)" ::: "memory"); \
                            __builtin_amdgcn_s_barrier(); } while (0)

// k_s byte swizzle: key (t>>3)&3 == lane-group of the column reads -> 2-way
__device__ __forceinline__ int ksw(int t) { return ((t >> 3) & 3) << 5; }

// vT/vwT swizzle: conflict-free transposed stores, b128-aligned reads
__device__ __forceinline__ int vt_off(int vc, int t) {
  int byte = vc * (VTSTR * 2) + t * 2;
  byte ^= ((vc >> 2) & 7) << 4;
  return byte >> 1;
}

// row fragment (non-swizzled: q_s, svt, sh)
__device__ __forceinline__ bf16x8 frag_row(const bf16* p, int stride, int row0,
                                           int kk0, int lane) {
  int row = row0 + (lane & 15);
  int kk = kk0 + ((lane >> 4) << 3);
  return *(const bf16x8*)(p + row * stride + kk);
}

// swizzled k_s row fragment (QK^T A operand)
__device__ __forceinline__ bf16x8 krow_frag(const bf16* ks_, int row0, int kk0,
                                            int lane) {
  int row = row0 + (lane & 15);
  int kk = kk0 + ((lane >> 4) << 3);
  int byte = (row * (QSTR * 2) + kk * 2) ^ ksw(row);
  return *(const bf16x8*)((const char*)ks_ + byte);
}

// swizzled k_s column fragment (state-update A operand), 8 scalar 2-way reads
__device__ __forceinline__ bf16x8 kcol_frag(const bf16* ks_, int T0, int kdA) {
  int C = ((T0 >> 3) & 3) << 5;
  int b0 = T0 * (QSTR * 2) + kdA * 2;
  bf16x8 f;
#pragma unroll
  for (int j = 0; j < 8; ++j)
    f[j] = *(const bf16*)((const char*)ks_ + ((b0 + j * (QSTR * 2)) ^ C));
  return f;
}

__device__ __forceinline__ void st4(bf16* p, float a, float b, float c, float d) {
  bf16x4 t;
  t[0] = (bf16)a; t[1] = (bf16)b; t[2] = (bf16)c; t[3] = (bf16)d;
  *(bf16x4*)p = t;
}

__device__ __forceinline__ void st8(bf16* p, const float4& a, const float4& b) {
  bf16x8 t;
  t[0] = (bf16)a.x; t[1] = (bf16)a.y; t[2] = (bf16)a.z; t[3] = (bf16)a.w;
  t[4] = (bf16)b.x; t[5] = (bf16)b.y; t[6] = (bf16)b.z; t[7] = (bf16)b.w;
  *(bf16x8*)p = t;  // 16B LDS store
}

// ---------------------------------------------------------------------------
// Pre-pass: KV_sub[bh][sub] = sum_{t in sub} k_t (v_t * w_t)^T  (internal
// chunk decays applied), Gsum_sub = total log-decay over the 1024 tokens.
// ---------------------------------------------------------------------------
__global__ void __launch_bounds__(512, 2)
gla_pre(const float* __restrict__ kg, const float* __restrict__ vg,
        const float* __restrict__ gg, float* __restrict__ ws)
{
  __shared__ __align__(16) bf16 k_s[2][BT * QSTR];
  __shared__ __align__(16) bf16 vwT_s[2][VD * VTSTR];
  __shared__ __align__(16) float gc_all[SEGC][BT];
  __shared__ float glast_all[SEGC];

  const int tid = threadIdx.x;
  const int wave = tid >> 6;
  const int lane = tid & 63;
  const int bh = blockIdx.x & 63;
  const int sub = blockIdx.x >> 6;     // 0..2

  const int jc = lane & 15;
  const int g4 = lane >> 4;
  const int r0 = g4 << 2;

  const size_t kbase = (size_t)bh * TLEN * KD + (size_t)sub * 1024 * KD;
  const size_t gbase = (size_t)bh * TLEN + (size_t)sub * 1024;
  const int vrow = tid >> 3;
  const int vcq = (tid & 7) << 2;

  float4 kpf[4], vpf[4];

  auto loadall = [&](int n) {
    const float4* k4 = (const float4*)(kg + kbase + (size_t)n * (BT * KD));
    kpf[0] = k4[2 * tid];        kpf[1] = k4[2 * tid + 1];
    kpf[2] = k4[1024 + 2 * tid]; kpf[3] = k4[1024 + 2 * tid + 1];
    const float* vrp = vg + kbase + (size_t)(n * BT + vrow) * VD + vcq;
#pragma unroll
    for (int q = 0; q < 4; ++q) vpf[q] = *(const float4*)(vrp + q * 32);
  };

  auto stage = [&](int buf, int n) {
#pragma unroll
    for (int i = 0; i < 2; ++i) {
      int row = i * 32 + (tid >> 4);
      int col0 = (tid & 15) << 3;
      int byte = (row * (QSTR * 2) + col0 * 2) ^ ksw(row);
      st8((bf16*)((char*)k_s[buf] + byte), kpf[2 * i], kpf[2 * i + 1]);
    }
    bf16* vwt = vwT_s[buf];
    float wv = __expf(glast_all[n] - gc_all[n][vrow]);
#pragma unroll
    for (int q = 0; q < 4; ++q) {
      const float* vp = (const float*)&vpf[q];
#pragma unroll
      for (int e = 0; e < 4; ++e)
        vwt[vt_off(vcq + q * 32 + e, vrow)] = (bf16)(vp[e] * wv);
    }
  };

  f32x4 S[8];
#pragma unroll
  for (int a = 0; a < 8; ++a) S[a] = {0.f, 0.f, 0.f, 0.f};

  loadall(0);
#pragma unroll 1
  for (int i = 0; i < 2; ++i) {     // wave w scans chunks 2w, 2w+1
    int cn = wave * 2 + i;
    float a = gg[gbase + cn * BT + lane];
#pragma unroll
    for (int off = 1; off < 64; off <<= 1) {
      float t = __shfl_up(a, off);
      if (lane >= off) a += t;
    }
    gc_all[cn][lane] = a;
    if (lane == 63) glast_all[cn] = a;
  }
  LGKM_BARRIER();
  stage(0, 0);
  loadall(1);
  LGKM_BARRIER();

#pragma unroll 1
  for (int n = 0; n < SEGC; ++n) {
    const int cur = n & 1;
    float dec = __expf(glast_all[n]);
#pragma unroll
    for (int a = 0; a < 8; ++a) S[a] *= dec;
#pragma unroll
    for (int ks = 0; ks < 2; ++ks) {
      bf16x8 ka = kcol_frag(k_s[cur], ks * 32 + (g4 << 3), wave * 16 + jc);
#pragma unroll
      for (int a = 0; a < 8; ++a) {
        bf16x8 b = *(const bf16x8*)(vwT_s[cur] + vt_off(16 * a + jc, ks * 32 + (g4 << 3)));
        S[a] = MFMA(ka, b, S[a], 0, 0, 0);
      }
    }
    if (n + 1 < SEGC) {
      stage(cur ^ 1, n + 1);
      if (n + 2 < SEGC) loadall(n + 2);
    }
    LGKM_BARRIER();
  }

  float* kv = ws + ((size_t)bh * 3 + sub) * KV_PER;
#pragma unroll
  for (int a = 0; a < 8; ++a)
#pragma unroll
    for (int r = 0; r < 4; ++r)
      kv[(wave * 16 + r0 + r) * VD + 16 * a + jc] = S[a][r];
  if (tid == 0) {
    float gs = 0.f;
    for (int n = 0; n < SEGC; ++n) gs += glast_all[n];
    ws[GS_OFF + bh * 3 + sub] = gs;
  }
}

// ---------------------------------------------------------------------------
// Main: full-V blocks, 16 chunks each, 2 barriers/chunk.
// P1: QK^T+gating+svt-export+state-update; P2: o_emit+store+stage(n+1).
// ---------------------------------------------------------------------------
__global__ void __launch_bounds__(512, 2)
gla_main(const float* __restrict__ qg, const float* __restrict__ kg,
         const float* __restrict__ vg, const float* __restrict__ gg,
         float* __restrict__ og, const float* __restrict__ ws)
{
  __shared__ __align__(16) bf16 q_s[BT * QSTR];        // 17.4 KB
  __shared__ __align__(16) bf16 k_s[BT * QSTR];        // 17.4 KB (swizzled)
  __shared__ __align__(16) bf16 vT_s[2][VD * VTSTR];   // 36.9 KB
  __shared__ __align__(16) bf16 vwT_s[2][VD * VTSTR];  // 36.9 KB
  __shared__ __align__(16) bf16 sh_s[BT * SHSTR];      // 9.2 KB
  __shared__ __align__(16) bf16 svt_s[VD * SVSTR];     // 34.8 KB (h_n [vc][kd])
  __shared__ __align__(16) float gc_all[SEGC][BT];     // 4.1 KB
  __shared__ float glast_all[SEGC];                    // total ~156.7 KB

  const int tid = threadIdx.x;
  const int wave = tid >> 6;
  const int lane = tid & 63;
  const int bh = blockIdx.x & 63;
  const int seg = blockIdx.x >> 6;     // 0..3

  const int jc = lane & 15;
  const int g4 = lane >> 4;
  const int r0 = g4 << 2;

  const int it = wave & 3;             // q-token tile (s cols, o rows)
  const int jt0 = (wave < 4) ? 0 : 2;  // k-token tiles {jt0, jt0+1}
  const int vq0 = (wave >> 2) << 2;    // o vc-16-tiles vq0..vq0+3

  const size_t qkbase = (size_t)bh * TLEN * KD + (size_t)seg * 1024 * KD;
  const size_t gbase = (size_t)bh * TLEN + (size_t)seg * 1024;
  const int vrow = tid >> 3;
  const int vcq = (tid & 7) << 2;

  float4 qpf[4], kpf[4], vpf[4];

  auto loadall = [&](int n) {
    const float4* q4 = (const float4*)(qg + qkbase + (size_t)n * (BT * KD));
    const float4* k4 = (const float4*)(kg + qkbase + (size_t)n * (BT * KD));
    qpf[0] = q4[2 * tid];        qpf[1] = q4[2 * tid + 1];
    qpf[2] = q4[1024 + 2 * tid]; qpf[3] = q4[1024 + 2 * tid + 1];
    kpf[0] = k4[2 * tid];        kpf[1] = k4[2 * tid + 1];
    kpf[2] = k4[1024 + 2 * tid]; kpf[3] = k4[1024 + 2 * tid + 1];
    const float* vrp = vg + qkbase + (size_t)(n * BT + vrow) * VD + vcq;
#pragma unroll
    for (int q = 0; q < 4; ++q) vpf[q] = *(const float4*)(vrp + q * 32);
  };

  auto stage = [&](int vbuf, int n) {
#pragma unroll
    for (int i = 0; i < 2; ++i) {
      int row = i * 32 + (tid >> 4);
      int col0 = (tid & 15) << 3;
      st8(&q_s[row * QSTR + col0], qpf[2 * i], qpf[2 * i + 1]);
      int byte = (row * (QSTR * 2) + col0 * 2) ^ ksw(row);
      st8((bf16*)((char*)k_s + byte), kpf[2 * i], kpf[2 * i + 1]);
    }
    bf16* vt = vT_s[vbuf];
    bf16* vwt = vwT_s[vbuf];
    float wv = __expf(glast_all[n] - gc_all[n][vrow]);
#pragma unroll
    for (int q = 0; q < 4; ++q) {
      const float* vp = (const float*)&vpf[q];
#pragma unroll
      for (int e = 0; e < 4; ++e) {
        int vc = vcq + q * 32 + e;
        vt[vt_off(vc, vrow)] = (bf16)vp[e];
        vwt[vt_off(vc, vrow)] = (bf16)(vp[e] * wv);
      }
    }
  };

  // state: S[a][r] = S[kd = wave*16 + r0 + r][vc = 16a + jc]
  f32x4 S[8];
#pragma unroll
  for (int a = 0; a < 8; ++a) S[a] = {0.f, 0.f, 0.f, 0.f};

  // entry state from pre-pass (seg > 0)
  if (seg > 0) {
    float D1 = __expf(ws[GS_OFF + bh * 3 + 1]);
    float D2 = __expf(ws[GS_OFF + bh * 3 + 2]);
    float mult[3];
    mult[0] = (seg == 1) ? 1.f : ((seg == 2) ? D1 : D1 * D2);
    mult[1] = (seg == 2) ? 1.f : D2;
    mult[2] = 1.f;
    for (int j = 0; j < seg && j < 3; ++j) {
      const float* kv = ws + ((size_t)bh * 3 + j) * KV_PER;
      float m = mult[j];
#pragma unroll
      for (int a = 0; a < 8; ++a)
#pragma unroll
        for (int r = 0; r < 4; ++r)
          S[a][r] += m * kv[(wave * 16 + r0 + r) * VD + 16 * a + jc];
    }
  }

  loadall(0);
#pragma unroll 1
  for (int i = 0; i < 2; ++i) {
    int cn = wave * 2 + i;
    float a = gg[gbase + cn * BT + lane];
#pragma unroll
    for (int off = 1; off < 64; off <<= 1) {
      float t = __shfl_up(a, off);
      if (lane >= off) a += t;
    }
    gc_all[cn][lane] = a;
    if (lane == 63) glast_all[cn] = a;
  }
  LGKM_BARRIER();
  stage(0, 0);
  loadall(1);
  LGKM_BARRIER();

#pragma unroll 1
  for (int n = 0; n < SEGC; ++n) {
    const int cur = n & 1;

    // ---------------- P1 ----------------
    bf16x8 af[4];
#pragma unroll
    for (int ks = 0; ks < 4; ++ks)
      af[ks] = frag_row(q_s, QSTR, it * 16, ks * 32, lane);

    // s^T = k q^T: lane holds rows j = jt*16+r0+r, col i = it*16+jc
    f32x4 sa0 = {0.f,0.f,0.f,0.f}, sa1 = {0.f,0.f,0.f,0.f};
#pragma unroll
    for (int ks = 0; ks < 4; ++ks) {
      bf16x8 a0 = krow_frag(k_s, jt0 * 16, ks * 32, lane);
      bf16x8 a1 = krow_frag(k_s, (jt0 + 1) * 16, ks * 32, lane);
      sa0 = MFMA(a0, af[ks], sa0, 0, 0, 0);
      sa1 = MFMA(a1, af[ks], sa1, 0, 0, 0);
    }
    {
      int i0 = it * 16 + jc;
      float gci = gc_all[n][i0];
#pragma unroll
      for (int t = 0; t < 2; ++t) {
        f32x4 sv = t ? sa1 : sa0;
        int jb = (jt0 + t) * 16 + r0;
        float4 g4v = *(const float4*)&gc_all[n][jb];
        const float* gj = (const float*)&g4v;
        bf16x4 pk;
#pragma unroll
        for (int r = 0; r < 4; ++r) {
          float val = (i0 >= jb + r) ? sv[r] * __expf(gci - gj[r]) * SCALE : 0.f;
          pk[r] = (bf16)val;
        }
        *(bf16x4*)&sh_s[i0 * SHSTR + jb] = pk;
      }
    }

    // export h_n (pre-update state)
#pragma unroll
    for (int a = 0; a < 8; ++a)
      st4(&svt_s[(16 * a + jc) * SVSTR + wave * 16 + r0],
          S[a][0], S[a][1], S[a][2], S[a][3]);

    // state update (skip on last chunk; final state unused)
    if (n + 1 < SEGC) {
      float dec = __expf(glast_all[n]);
#pragma unroll
      for (int a = 0; a < 8; ++a) S[a] *= dec;
#pragma unroll
      for (int ks = 0; ks < 2; ++ks) {
        bf16x8 ka = kcol_frag(k_s, ks * 32 + (g4 << 3), wave * 16 + jc);
#pragma unroll
        for (int a = 0; a < 8; ++a) {
          bf16x8 b = *(const bf16x8*)(vwT_s[cur] + vt_off(16 * a + jc, ks * 32 + (g4 << 3)));
          S[a] = MFMA(ka, b, S[a], 0, 0, 0);
        }
      }
    }
    LGKM_BARRIER();

    // ---------------- P2 ----------------
    {
      bf16x8 sha[2];
#pragma unroll
      for (int ks = 0; ks < 2; ++ks)
        sha[ks] = frag_row(sh_s, SHSTR, it * 16, ks * 32, lane);
      float eg[4];
      {
        float4 e4 = *(const float4*)&gc_all[n][it * 16 + r0];
        const float* ep = (const float*)&e4;
#pragma unroll
        for (int r = 0; r < 4; ++r) eg[r] = __expf(ep[r]) * SCALE;
      }
#pragma unroll
      for (int p = 0; p < 4; ++p) {
        int vq = vq0 + p;
        f32x4 oacc = {0.f, 0.f, 0.f, 0.f};
#pragma unroll
        for (int ks = 0; ks < 4; ++ks) {  // o_inter = q @ h_n
          bf16x8 b = frag_row(svt_s, SVSTR, vq * 16, ks * 32, lane);
          oacc = MFMA(af[ks], b, oacc, 0, 0, 0);
        }
#pragma unroll
        for (int r = 0; r < 4; ++r) oacc[r] *= eg[r];
#pragma unroll
        for (int ks = 0; ks < 2; ++ks) {  // o_intra = s-hat @ v
          bf16x8 b = *(const bf16x8*)(vT_s[cur] + vt_off(vq * 16 + jc, ks * 32 + (g4 << 3)));
          oacc = MFMA(sha[ks], b, oacc, 0, 0, 0);
        }
#pragma unroll
        for (int r = 0; r < 4; ++r) {
          int row = it * 16 + r0 + r;
          og[qkbase + (size_t)(n * BT + row) * VD + vq * 16 + jc] = oacc[r];
        }
      }
    }
    if (n + 1 < SEGC) {
      stage(cur ^ 1, n + 1);
      if (n + 2 < SEGC) loadall(n + 2);
    }
    LGKM_BARRIER();
  }
}

// ---------------------------------------------------------------------------
// Legacy R6 kernel (fallback if d_ws is too small for the pre-pass).
// ---------------------------------------------------------------------------
__global__ void __launch_bounds__(512, 2)
gla_fused(const float* __restrict__ qg, const float* __restrict__ kg,
          const float* __restrict__ vg, const float* __restrict__ gg,
          float* __restrict__ og)
{
  __shared__ __align__(16) bf16 q_s[2][BT * QSTR];
  __shared__ __align__(16) bf16 k_s[2][BT * QSTR];
  __shared__ __align__(16) bf16 vT_s[3][VSG * VTSTR];
  __shared__ __align__(16) bf16 vwT_s[3][VSG * VTSTR];
  __shared__ __align__(16) bf16 sh_s[2][BT * SHSTR];
  __shared__ __align__(16) bf16 svt_s[2][VSG * SVSTR];
  __shared__ __align__(16) float gc_all[NCHUNK][BT];
  __shared__ float glast_all[NCHUNK];

  const int tid = threadIdx.x;
  const int wave = tid >> 6;
  const int lane = tid & 63;
  const int bh = blockIdx.x & 63;
  const int vseg = blockIdx.x >> 6;

  const int jc = lane & 15;
  const int g4 = lane >> 4;
  const int r0 = g4 << 2;

  const int it = wave & 3;
  const int nt = wave >> 2;
  const int jt0 = (wave < 4) ? 0 : 2;

  const size_t qkbase = (size_t)bh * TLEN * KD;
  const size_t gbase = (size_t)bh * TLEN;
  const size_t vbase = (size_t)bh * TLEN * VD + (size_t)vseg * VSG;
  const int vrow = tid >> 3;
  const int vc0 = (tid & 7) << 2;

  float4 qpf[4], kpf[4], vpf;

  auto loadpf = [&](int n) {
    const float4* q4 = (const float4*)(qg + qkbase + (size_t)n * (BT * KD));
    const float4* k4 = (const float4*)(kg + qkbase + (size_t)n * (BT * KD));
#pragma unroll
    for (int i = 0; i < 4; ++i) { qpf[i] = q4[i * 512 + tid]; kpf[i] = k4[i * 512 + tid]; }
    vpf = *(const float4*)(vg + vbase + (size_t)(n * BT + vrow) * VD + vc0);
  };

  auto stage = [&](int b2, int b3, int n) {
#pragma unroll
    for (int i = 0; i < 4; ++i) {
      int f4 = i * 512 + tid;
      int t = f4 >> 5;
      int kd0 = (f4 & 31) << 2;
      st4(&q_s[b2][t * QSTR + kd0], qpf[i].x, qpf[i].y, qpf[i].z, qpf[i].w);
      int byte = (t * (QSTR * 2) + kd0 * 2) ^ ksw(t);
      st4((bf16*)((char*)k_s[b2] + byte), kpf[i].x, kpf[i].y, kpf[i].z, kpf[i].w);
    }
    bf16* vt = vT_s[b3];
    bf16* vwt = vwT_s[b3];
    float wv = __expf(glast_all[n] - gc_all[n][vrow]);
    vt[vt_off(vc0 + 0, vrow)] = (bf16)vpf.x;
    vt[vt_off(vc0 + 1, vrow)] = (bf16)vpf.y;
    vt[vt_off(vc0 + 2, vrow)] = (bf16)vpf.z;
    vt[vt_off(vc0 + 3, vrow)] = (bf16)vpf.w;
    vwt[vt_off(vc0 + 0, vrow)] = (bf16)(vpf.x * wv);
    vwt[vt_off(vc0 + 1, vrow)] = (bf16)(vpf.y * wv);
    vwt[vt_off(vc0 + 2, vrow)] = (bf16)(vpf.z * wv);
    vwt[vt_off(vc0 + 3, vrow)] = (bf16)(vpf.w * wv);
  };

  auto o_emit = [&](int no, int b2o, int b3o, const bf16x8 (&afp)[4]) {
    f32x4 oacc = {0.f, 0.f, 0.f, 0.f};
#pragma unroll
    for (int ks = 0; ks < 4; ++ks) {
      bf16x8 b = frag_row(svt_s[b2o], SVSTR, nt * 16, ks * 32, lane);
      oacc = MFMA(afp[ks], b, oacc, 0, 0, 0);
    }
    {
      float4 e4 = *(const float4*)&gc_all[no][it * 16 + r0];
      const float* ep = (const float*)&e4;
#pragma unroll
      for (int r = 0; r < 4; ++r) oacc[r] *= __expf(ep[r]) * SCALE;
    }
#pragma unroll
    for (int ks = 0; ks < 2; ++ks) {
      bf16x8 a = frag_row(sh_s[b2o], SHSTR, it * 16, ks * 32, lane);
      bf16x8 b = *(const bf16x8*)(vT_s[b3o] + vt_off(nt * 16 + jc, ks * 32 + (g4 << 3)));
      oacc = MFMA(a, b, oacc, 0, 0, 0);
    }
#pragma unroll
    for (int r = 0; r < 4; ++r) {
      int row = it * 16 + r0 + r;
      og[vbase + (size_t)(no * BT + row) * VD + nt * 16 + jc] = oacc[r];
    }
  };

  f32x4 Sa = {0.f, 0.f, 0.f, 0.f}, Sb = {0.f, 0.f, 0.f, 0.f};
  bf16x8 afp[4];

  loadpf(0);
#pragma unroll 1
  for (int i = 0; i < 8; ++i) {
    int cn = wave * 8 + i;
    float a = gg[gbase + cn * BT + lane];
#pragma unroll
    for (int off = 1; off < 64; off <<= 1) {
      float t = __shfl_up(a, off);
      if (lane >= off) a += t;
    }
    gc_all[cn][lane] = a;
    if (lane == 63) glast_all[cn] = a;
  }
  LGKM_BARRIER();
  stage(0, 0, 0);
  loadpf(1);
  LGKM_BARRIER();

  int b3 = 0;
#pragma unroll 1
  for (int n = 0; n < NCHUNK; ++n) {
    const int b2 = n & 1;
    const int b3n = (b3 == 2) ? 0 : b3 + 1;
    const int b3p = (b3 == 0) ? 2 : b3 - 1;

    if (n > 0) o_emit(n - 1, b2 ^ 1, b3p, afp);

    bf16x8 af[4];
#pragma unroll
    for (int ks = 0; ks < 4; ++ks)
      af[ks] = frag_row(q_s[b2], QSTR, it * 16, ks * 32, lane);

    f32x4 sa0 = {0.f,0.f,0.f,0.f}, sa1 = {0.f,0.f,0.f,0.f};
#pragma unroll
    for (int ks = 0; ks < 4; ++ks) {
      bf16x8 a0 = krow_frag(k_s[b2], jt0 * 16, ks * 32, lane);
      bf16x8 a1 = krow_frag(k_s[b2], (jt0 + 1) * 16, ks * 32, lane);
      sa0 = MFMA(a0, af[ks], sa0, 0, 0, 0);
      sa1 = MFMA(a1, af[ks], sa1, 0, 0, 0);
    }
    {
      int i0 = it * 16 + jc;
      float gci = gc_all[n][i0];
#pragma unroll
      for (int t = 0; t < 2; ++t) {
        f32x4 sv = t ? sa1 : sa0;
        int jb = (jt0 + t) * 16 + r0;
        float4 g4v = *(const float4*)&gc_all[n][jb];
        const float* gj = (const float*)&g4v;
        bf16x4 pk;
#pragma unroll
        for (int r = 0; r < 4; ++r) {
          float val = (i0 >= jb + r) ? sv[r] * __expf(gci - gj[r]) * SCALE : 0.f;
          pk[r] = (bf16)val;
        }
        *(bf16x4*)&sh_s[b2][i0 * SHSTR + jb] = pk;
      }
    }

    st4(&svt_s[b2][jc * SVSTR + wave * 16 + r0], Sa[0], Sa[1], Sa[2], Sa[3]);
    st4(&svt_s[b2][(16 + jc) * SVSTR + wave * 16 + r0], Sb[0], Sb[1], Sb[2], Sb[3]);
    {
      float dec = __expf(glast_all[n]);
#pragma unroll
      for (int r = 0; r < 4; ++r) { Sa[r] *= dec; Sb[r] *= dec; }
#pragma unroll
      for (int ks = 0; ks < 2; ++ks) {
        bf16x8 a = kcol_frag(k_s[b2], ks * 32 + (g4 << 3), wave * 16 + jc);
        bf16x8 b0 = *(const bf16x8*)(vwT_s[b3] + vt_off(jc, ks * 32 + (g4 << 3)));
        bf16x8 b1 = *(const bf16x8*)(vwT_s[b3] + vt_off(16 + jc, ks * 32 + (g4 << 3)));
        Sa = MFMA(a, b0, Sa, 0, 0, 0);
        Sb = MFMA(a, b1, Sb, 0, 0, 0);
      }
    }

    if (n + 1 < NCHUNK) {
      stage(b2 ^ 1, b3n, n + 1);
      if (n + 2 < NCHUNK) loadpf(n + 2);
    }

#pragma unroll
    for (int ks = 0; ks < 4; ++ks) afp[ks] = af[ks];
    b3 = b3n;

    LGKM_BARRIER();
  }

  o_emit(NCHUNK - 1, 1, 0, afp);
}

extern "C" void kernel_launch(void* const* d_in, const int* in_sizes, int n_in,
                              void* d_out, int out_size, void* d_ws, size_t ws_size,
                              hipStream_t stream) {
  const float* q = (const float*)d_in[0];
  const float* k = (const float*)d_in[1];
  const float* v = (const float*)d_in[2];
  const float* g = (const float*)d_in[3];
  float* o = (float*)d_out;
  if (ws_size >= WS_NEED) {
    float* ws = (float*)d_ws;
    gla_pre<<<dim3(192), dim3(512), 0, stream>>>(k, v, g, ws);
    gla_main<<<dim3(256), dim3(512), 0, stream>>>(q, k, v, g, o, ws);
  } else {
    gla_fused<<<dim3(256), dim3(512), 0, stream>>>(q, k, v, g, o);
  }
}

// Round 8
// 168.481 us; speedup vs baseline: 1.0310x; 1.0310x over previous
//
#include <hip/hip_runtime.h>
#include <hip/hip_bf16.h>

// Chunked simple-GLA forward, B=2 H=32 T=4096 K=V=128, BT=64.
// Two-kernel T-split (P=4 segments):
//   gla_pre : 192 blocks (64 bh x 3 subsegs) compute per-1024-token KV sums
//             + gate totals into d_ws (pure weighted sums, fully parallel).
//   gla_main: 256 blocks (64 bh x 4 segments), FULL V=128 per block,
//             16 sequential chunks, entry state combined from ws.
// Falls back to the R6 single-kernel (gla_fused) if ws is too small.

#define BT 64
#define KD 128
#define VD 128
#define VSG 32          // legacy kernel's v-segment width
#define NCHUNK 64       // legacy
#define SEGC 16         // chunks per segment (new)
#define TLEN 4096
#define SCALE 0.08838834764831845f   // 128^-0.5

#define QSTR 136
#define SHSTR 72
#define SVSTR 136
#define VTSTR 72

#define KV_PER 16384                    // floats per KV block (128x128)
#define KV_TOT (64 * 3 * KV_PER)
#define GS_OFF KV_TOT
#define WS_NEED ((size_t)(KV_TOT + 192) * 4)

typedef __bf16 bf16;
typedef __bf16 bf16x8 __attribute__((ext_vector_type(8)));
typedef __bf16 bf16x4 __attribute__((ext_vector_type(4)));
typedef float f32x4 __attribute__((ext_vector_type(4)));

#define MFMA __builtin_amdgcn_mfma_f32_16x16x32_bf16
#define LGKM_BARRIER() do { asm volatile("s_waitcnt lgkmcnt(0)" ::: "memory"); \
                            __builtin_amdgcn_s_barrier(); } while (0)

// k_s byte swizzle: key (t>>3)&3 == lane-group of the column reads -> 2-way
__device__ __forceinline__ int ksw(int t) { return ((t >> 3) & 3) << 5; }

// vT/vwT swizzle: conflict-free transposed stores, b128-aligned reads
__device__ __forceinline__ int vt_off(int vc, int t) {
  int byte = vc * (VTSTR * 2) + t * 2;
  byte ^= ((vc >> 2) & 7) << 4;
  return byte >> 1;
}

// row fragment (non-swizzled: q_s, svt, sh)
__device__ __forceinline__ bf16x8 frag_row(const bf16* p, int stride, int row0,
                                           int kk0, int lane) {
  int row = row0 + (lane & 15);
  int kk = kk0 + ((lane >> 4) << 3);
  return *(const bf16x8*)(p + row * stride + kk);
}

// swizzled k_s row fragment (QK^T A operand)
__device__ __forceinline__ bf16x8 krow_frag(const bf16* ks_, int row0, int kk0,
                                            int lane) {
  int row = row0 + (lane & 15);
  int kk = kk0 + ((lane >> 4) << 3);
  int byte = (row * (QSTR * 2) + kk * 2) ^ ksw(row);
  return *(const bf16x8*)((const char*)ks_ + byte);
}

// swizzled k_s column fragment (state-update A operand), 8 scalar 2-way reads
__device__ __forceinline__ bf16x8 kcol_frag(const bf16* ks_, int T0, int kdA) {
  int C = ((T0 >> 3) & 3) << 5;
  int b0 = T0 * (QSTR * 2) + kdA * 2;
  bf16x8 f;
#pragma unroll
  for (int j = 0; j < 8; ++j)
    f[j] = *(const bf16*)((const char*)ks_ + ((b0 + j * (QSTR * 2)) ^ C));
  return f;
}

__device__ __forceinline__ void st4(bf16* p, float a, float b, float c, float d) {
  bf16x4 t;
  t[0] = (bf16)a; t[1] = (bf16)b; t[2] = (bf16)c; t[3] = (bf16)d;
  *(bf16x4*)p = t;
}

__device__ __forceinline__ void st8(bf16* p, const float4& a, const float4& b) {
  bf16x8 t;
  t[0] = (bf16)a.x; t[1] = (bf16)a.y; t[2] = (bf16)a.z; t[3] = (bf16)a.w;
  t[4] = (bf16)b.x; t[5] = (bf16)b.y; t[6] = (bf16)b.z; t[7] = (bf16)b.w;
  *(bf16x8*)p = t;  // 16B LDS store
}

// ---------------------------------------------------------------------------
// Pre-pass: KV_sub[bh][sub] = sum_{t in sub} k_t (v_t * w_t)^T  (internal
// chunk decays applied), Gsum_sub = total log-decay over the 1024 tokens.
// ---------------------------------------------------------------------------
__global__ void __launch_bounds__(512, 2)
gla_pre(const float* __restrict__ kg, const float* __restrict__ vg,
        const float* __restrict__ gg, float* __restrict__ ws)
{
  __shared__ __align__(16) bf16 k_s[2][BT * QSTR];
  __shared__ __align__(16) bf16 vwT_s[2][VD * VTSTR];
  __shared__ __align__(16) float gc_all[SEGC][BT];
  __shared__ float glast_all[SEGC];

  const int tid = threadIdx.x;
  const int wave = tid >> 6;
  const int lane = tid & 63;
  const int bh = blockIdx.x & 63;
  const int sub = blockIdx.x >> 6;     // 0..2

  const int jc = lane & 15;
  const int g4 = lane >> 4;
  const int r0 = g4 << 2;

  const size_t kbase = (size_t)bh * TLEN * KD + (size_t)sub * 1024 * KD;
  const size_t gbase = (size_t)bh * TLEN + (size_t)sub * 1024;
  const int vrow = tid >> 3;
  const int vcq = (tid & 7) << 2;

  float4 kpf[4], vpf[4];

  auto loadall = [&](int n) {
    const float4* k4 = (const float4*)(kg + kbase + (size_t)n * (BT * KD));
    kpf[0] = k4[2 * tid];        kpf[1] = k4[2 * tid + 1];
    kpf[2] = k4[1024 + 2 * tid]; kpf[3] = k4[1024 + 2 * tid + 1];
    const float* vrp = vg + kbase + (size_t)(n * BT + vrow) * VD + vcq;
#pragma unroll
    for (int q = 0; q < 4; ++q) vpf[q] = *(const float4*)(vrp + q * 32);
  };

  auto stage = [&](int buf, int n) {
#pragma unroll
    for (int i = 0; i < 2; ++i) {
      int row = i * 32 + (tid >> 4);
      int col0 = (tid & 15) << 3;
      int byte = (row * (QSTR * 2) + col0 * 2) ^ ksw(row);
      st8((bf16*)((char*)k_s[buf] + byte), kpf[2 * i], kpf[2 * i + 1]);
    }
    bf16* vwt = vwT_s[buf];
    float wv = __expf(glast_all[n] - gc_all[n][vrow]);
#pragma unroll
    for (int q = 0; q < 4; ++q) {
      const float* vp = (const float*)&vpf[q];
#pragma unroll
      for (int e = 0; e < 4; ++e)
        vwt[vt_off(vcq + q * 32 + e, vrow)] = (bf16)(vp[e] * wv);
    }
  };

  f32x4 S[8];
#pragma unroll
  for (int a = 0; a < 8; ++a) S[a] = {0.f, 0.f, 0.f, 0.f};

  loadall(0);
#pragma unroll 1
  for (int i = 0; i < 2; ++i) {     // wave w scans chunks 2w, 2w+1
    int cn = wave * 2 + i;
    float a = gg[gbase + cn * BT + lane];
#pragma unroll
    for (int off = 1; off < 64; off <<= 1) {
      float t = __shfl_up(a, off);
      if (lane >= off) a += t;
    }
    gc_all[cn][lane] = a;
    if (lane == 63) glast_all[cn] = a;
  }
  LGKM_BARRIER();
  stage(0, 0);
  loadall(1);
  LGKM_BARRIER();

#pragma unroll 1
  for (int n = 0; n < SEGC; ++n) {
    const int cur = n & 1;
    float dec = __expf(glast_all[n]);
#pragma unroll
    for (int a = 0; a < 8; ++a) S[a] *= dec;
#pragma unroll
    for (int ks = 0; ks < 2; ++ks) {
      bf16x8 ka = kcol_frag(k_s[cur], ks * 32 + (g4 << 3), wave * 16 + jc);
#pragma unroll
      for (int a = 0; a < 8; ++a) {
        bf16x8 b = *(const bf16x8*)(vwT_s[cur] + vt_off(16 * a + jc, ks * 32 + (g4 << 3)));
        S[a] = MFMA(ka, b, S[a], 0, 0, 0);
      }
    }
    if (n + 1 < SEGC) {
      stage(cur ^ 1, n + 1);
      if (n + 2 < SEGC) loadall(n + 2);
    }
    LGKM_BARRIER();
  }

  float* kv = ws + ((size_t)bh * 3 + sub) * KV_PER;
#pragma unroll
  for (int a = 0; a < 8; ++a)
#pragma unroll
    for (int r = 0; r < 4; ++r)
      kv[(wave * 16 + r0 + r) * VD + 16 * a + jc] = S[a][r];
  if (tid == 0) {
    float gs = 0.f;
    for (int n = 0; n < SEGC; ++n) gs += glast_all[n];
    ws[GS_OFF + bh * 3 + sub] = gs;
  }
}

// ---------------------------------------------------------------------------
// Main: full-V blocks, 16 chunks each, 2 barriers/chunk.
// P1: QK^T+gating+svt-export+state-update; P2: o_emit+store+stage(n+1).
// ---------------------------------------------------------------------------
__global__ void __launch_bounds__(512, 2)
gla_main(const float* __restrict__ qg, const float* __restrict__ kg,
         const float* __restrict__ vg, const float* __restrict__ gg,
         float* __restrict__ og, const float* __restrict__ ws)
{
  __shared__ __align__(16) bf16 q_s[BT * QSTR];        // 17.4 KB
  __shared__ __align__(16) bf16 k_s[BT * QSTR];        // 17.4 KB (swizzled)
  __shared__ __align__(16) bf16 vT_s[2][VD * VTSTR];   // 36.9 KB
  __shared__ __align__(16) bf16 vwT_s[2][VD * VTSTR];  // 36.9 KB
  __shared__ __align__(16) bf16 sh_s[BT * SHSTR];      // 9.2 KB
  __shared__ __align__(16) bf16 svt_s[VD * SVSTR];     // 34.8 KB (h_n [vc][kd])
  __shared__ __align__(16) float gc_all[SEGC][BT];     // 4.1 KB
  __shared__ float glast_all[SEGC];                    // total ~156.7 KB

  const int tid = threadIdx.x;
  const int wave = tid >> 6;
  const int lane = tid & 63;
  const int bh = blockIdx.x & 63;
  const int seg = blockIdx.x >> 6;     // 0..3

  const int jc = lane & 15;
  const int g4 = lane >> 4;
  const int r0 = g4 << 2;

  const int it = wave & 3;             // q-token tile (s cols, o rows)
  const int jt0 = (wave < 4) ? 0 : 2;  // k-token tiles {jt0, jt0+1}
  const int vq0 = (wave >> 2) << 2;    // o vc-16-tiles vq0..vq0+3

  const size_t qkbase = (size_t)bh * TLEN * KD + (size_t)seg * 1024 * KD;
  const size_t gbase = (size_t)bh * TLEN + (size_t)seg * 1024;
  const int vrow = tid >> 3;
  const int vcq = (tid & 7) << 2;

  float4 qpf[4], kpf[4], vpf[4];

  auto loadall = [&](int n) {
    const float4* q4 = (const float4*)(qg + qkbase + (size_t)n * (BT * KD));
    const float4* k4 = (const float4*)(kg + qkbase + (size_t)n * (BT * KD));
    qpf[0] = q4[2 * tid];        qpf[1] = q4[2 * tid + 1];
    qpf[2] = q4[1024 + 2 * tid]; qpf[3] = q4[1024 + 2 * tid + 1];
    kpf[0] = k4[2 * tid];        kpf[1] = k4[2 * tid + 1];
    kpf[2] = k4[1024 + 2 * tid]; kpf[3] = k4[1024 + 2 * tid + 1];
    const float* vrp = vg + qkbase + (size_t)(n * BT + vrow) * VD + vcq;
#pragma unroll
    for (int q = 0; q < 4; ++q) vpf[q] = *(const float4*)(vrp + q * 32);
  };

  auto stage = [&](int vbuf, int n) {
#pragma unroll
    for (int i = 0; i < 2; ++i) {
      int row = i * 32 + (tid >> 4);
      int col0 = (tid & 15) << 3;
      st8(&q_s[row * QSTR + col0], qpf[2 * i], qpf[2 * i + 1]);
      int byte = (row * (QSTR * 2) + col0 * 2) ^ ksw(row);
      st8((bf16*)((char*)k_s + byte), kpf[2 * i], kpf[2 * i + 1]);
    }
    bf16* vt = vT_s[vbuf];
    bf16* vwt = vwT_s[vbuf];
    float wv = __expf(glast_all[n] - gc_all[n][vrow]);
#pragma unroll
    for (int q = 0; q < 4; ++q) {
      const float* vp = (const float*)&vpf[q];
#pragma unroll
      for (int e = 0; e < 4; ++e) {
        int vc = vcq + q * 32 + e;
        vt[vt_off(vc, vrow)] = (bf16)vp[e];
        vwt[vt_off(vc, vrow)] = (bf16)(vp[e] * wv);
      }
    }
  };

  // state: S[a][r] = S[kd = wave*16 + r0 + r][vc = 16a + jc]
  f32x4 S[8];
#pragma unroll
  for (int a = 0; a < 8; ++a) S[a] = {0.f, 0.f, 0.f, 0.f};

  // entry state from pre-pass (seg > 0)
  if (seg > 0) {
    float D1 = __expf(ws[GS_OFF + bh * 3 + 1]);
    float D2 = __expf(ws[GS_OFF + bh * 3 + 2]);
    float mult[3];
    mult[0] = (seg == 1) ? 1.f : ((seg == 2) ? D1 : D1 * D2);
    mult[1] = (seg == 2) ? 1.f : D2;
    mult[2] = 1.f;
    for (int j = 0; j < seg && j < 3; ++j) {
      const float* kv = ws + ((size_t)bh * 3 + j) * KV_PER;
      float m = mult[j];
#pragma unroll
      for (int a = 0; a < 8; ++a)
#pragma unroll
        for (int r = 0; r < 4; ++r)
          S[a][r] += m * kv[(wave * 16 + r0 + r) * VD + 16 * a + jc];
    }
  }

  loadall(0);
#pragma unroll 1
  for (int i = 0; i < 2; ++i) {
    int cn = wave * 2 + i;
    float a = gg[gbase + cn * BT + lane];
#pragma unroll
    for (int off = 1; off < 64; off <<= 1) {
      float t = __shfl_up(a, off);
      if (lane >= off) a += t;
    }
    gc_all[cn][lane] = a;
    if (lane == 63) glast_all[cn] = a;
  }
  LGKM_BARRIER();
  stage(0, 0);
  loadall(1);
  LGKM_BARRIER();

#pragma unroll 1
  for (int n = 0; n < SEGC; ++n) {
    const int cur = n & 1;

    // ---------------- P1 ----------------
    bf16x8 af[4];
#pragma unroll
    for (int ks = 0; ks < 4; ++ks)
      af[ks] = frag_row(q_s, QSTR, it * 16, ks * 32, lane);

    // s^T = k q^T: lane holds rows j = jt*16+r0+r, col i = it*16+jc
    f32x4 sa0 = {0.f,0.f,0.f,0.f}, sa1 = {0.f,0.f,0.f,0.f};
#pragma unroll
    for (int ks = 0; ks < 4; ++ks) {
      bf16x8 a0 = krow_frag(k_s, jt0 * 16, ks * 32, lane);
      bf16x8 a1 = krow_frag(k_s, (jt0 + 1) * 16, ks * 32, lane);
      sa0 = MFMA(a0, af[ks], sa0, 0, 0, 0);
      sa1 = MFMA(a1, af[ks], sa1, 0, 0, 0);
    }
    {
      int i0 = it * 16 + jc;
      float gci = gc_all[n][i0];
#pragma unroll
      for (int t = 0; t < 2; ++t) {
        f32x4 sv = t ? sa1 : sa0;
        int jb = (jt0 + t) * 16 + r0;
        float4 g4v = *(const float4*)&gc_all[n][jb];
        const float* gj = (const float*)&g4v;
        bf16x4 pk;
#pragma unroll
        for (int r = 0; r < 4; ++r) {
          float val = (i0 >= jb + r) ? sv[r] * __expf(gci - gj[r]) * SCALE : 0.f;
          pk[r] = (bf16)val;
        }
        *(bf16x4*)&sh_s[i0 * SHSTR + jb] = pk;
      }
    }

    // export h_n (pre-update state)
#pragma unroll
    for (int a = 0; a < 8; ++a)
      st4(&svt_s[(16 * a + jc) * SVSTR + wave * 16 + r0],
          S[a][0], S[a][1], S[a][2], S[a][3]);

    // state update (skip on last chunk; final state unused)
    if (n + 1 < SEGC) {
      float dec = __expf(glast_all[n]);
#pragma unroll
      for (int a = 0; a < 8; ++a) S[a] *= dec;
#pragma unroll
      for (int ks = 0; ks < 2; ++ks) {
        bf16x8 ka = kcol_frag(k_s, ks * 32 + (g4 << 3), wave * 16 + jc);
#pragma unroll
        for (int a = 0; a < 8; ++a) {
          bf16x8 b = *(const bf16x8*)(vwT_s[cur] + vt_off(16 * a + jc, ks * 32 + (g4 << 3)));
          S[a] = MFMA(ka, b, S[a], 0, 0, 0);
        }
      }
    }
    LGKM_BARRIER();

    // ---------------- P2 ----------------
    {
      bf16x8 sha[2];
#pragma unroll
      for (int ks = 0; ks < 2; ++ks)
        sha[ks] = frag_row(sh_s, SHSTR, it * 16, ks * 32, lane);
      float eg[4];
      {
        float4 e4 = *(const float4*)&gc_all[n][it * 16 + r0];
        const float* ep = (const float*)&e4;
#pragma unroll
        for (int r = 0; r < 4; ++r) eg[r] = __expf(ep[r]) * SCALE;
      }
#pragma unroll
      for (int p = 0; p < 4; ++p) {
        int vq = vq0 + p;
        f32x4 oacc = {0.f, 0.f, 0.f, 0.f};
#pragma unroll
        for (int ks = 0; ks < 4; ++ks) {  // o_inter = q @ h_n
          bf16x8 b = frag_row(svt_s, SVSTR, vq * 16, ks * 32, lane);
          oacc = MFMA(af[ks], b, oacc, 0, 0, 0);
        }
#pragma unroll
        for (int r = 0; r < 4; ++r) oacc[r] *= eg[r];
#pragma unroll
        for (int ks = 0; ks < 2; ++ks) {  // o_intra = s-hat @ v
          bf16x8 b = *(const bf16x8*)(vT_s[cur] + vt_off(vq * 16 + jc, ks * 32 + (g4 << 3)));
          oacc = MFMA(sha[ks], b, oacc, 0, 0, 0);
        }
#pragma unroll
        for (int r = 0; r < 4; ++r) {
          int row = it * 16 + r0 + r;
          og[qkbase + (size_t)(n * BT + row) * VD + vq * 16 + jc] = oacc[r];
        }
      }
    }
    if (n + 1 < SEGC) {
      stage(cur ^ 1, n + 1);
      if (n + 2 < SEGC) loadall(n + 2);
    }
    LGKM_BARRIER();
  }
}

// ---------------------------------------------------------------------------
// Legacy R6 kernel (fallback if d_ws is too small for the pre-pass).
// ---------------------------------------------------------------------------
__global__ void __launch_bounds__(512, 2)
gla_fused(const float* __restrict__ qg, const float* __restrict__ kg,
          const float* __restrict__ vg, const float* __restrict__ gg,
          float* __restrict__ og)
{
  __shared__ __align__(16) bf16 q_s[2][BT * QSTR];
  __shared__ __align__(16) bf16 k_s[2][BT * QSTR];
  __shared__ __align__(16) bf16 vT_s[3][VSG * VTSTR];
  __shared__ __align__(16) bf16 vwT_s[3][VSG * VTSTR];
  __shared__ __align__(16) bf16 sh_s[2][BT * SHSTR];
  __shared__ __align__(16) bf16 svt_s[2][VSG * SVSTR];
  __shared__ __align__(16) float gc_all[NCHUNK][BT];
  __shared__ float glast_all[NCHUNK];

  const int tid = threadIdx.x;
  const int wave = tid >> 6;
  const int lane = tid & 63;
  const int bh = blockIdx.x & 63;
  const int vseg = blockIdx.x >> 6;

  const int jc = lane & 15;
  const int g4 = lane >> 4;
  const int r0 = g4 << 2;

  const int it = wave & 3;
  const int nt = wave >> 2;
  const int jt0 = (wave < 4) ? 0 : 2;

  const size_t qkbase = (size_t)bh * TLEN * KD;
  const size_t gbase = (size_t)bh * TLEN;
  const size_t vbase = (size_t)bh * TLEN * VD + (size_t)vseg * VSG;
  const int vrow = tid >> 3;
  const int vc0 = (tid & 7) << 2;

  float4 qpf[4], kpf[4], vpf;

  auto loadpf = [&](int n) {
    const float4* q4 = (const float4*)(qg + qkbase + (size_t)n * (BT * KD));
    const float4* k4 = (const float4*)(kg + qkbase + (size_t)n * (BT * KD));
#pragma unroll
    for (int i = 0; i < 4; ++i) { qpf[i] = q4[i * 512 + tid]; kpf[i] = k4[i * 512 + tid]; }
    vpf = *(const float4*)(vg + vbase + (size_t)(n * BT + vrow) * VD + vc0);
  };

  auto stage = [&](int b2, int b3, int n) {
#pragma unroll
    for (int i = 0; i < 4; ++i) {
      int f4 = i * 512 + tid;
      int t = f4 >> 5;
      int kd0 = (f4 & 31) << 2;
      st4(&q_s[b2][t * QSTR + kd0], qpf[i].x, qpf[i].y, qpf[i].z, qpf[i].w);
      int byte = (t * (QSTR * 2) + kd0 * 2) ^ ksw(t);
      st4((bf16*)((char*)k_s[b2] + byte), kpf[i].x, kpf[i].y, kpf[i].z, kpf[i].w);
    }
    bf16* vt = vT_s[b3];
    bf16* vwt = vwT_s[b3];
    float wv = __expf(glast_all[n] - gc_all[n][vrow]);
    vt[vt_off(vc0 + 0, vrow)] = (bf16)vpf.x;
    vt[vt_off(vc0 + 1, vrow)] = (bf16)vpf.y;
    vt[vt_off(vc0 + 2, vrow)] = (bf16)vpf.z;
    vt[vt_off(vc0 + 3, vrow)] = (bf16)vpf.w;
    vwt[vt_off(vc0 + 0, vrow)] = (bf16)(vpf.x * wv);
    vwt[vt_off(vc0 + 1, vrow)] = (bf16)(vpf.y * wv);
    vwt[vt_off(vc0 + 2, vrow)] = (bf16)(vpf.z * wv);
    vwt[vt_off(vc0 + 3, vrow)] = (bf16)(vpf.w * wv);
  };

  auto o_emit = [&](int no, int b2o, int b3o, const bf16x8 (&afp)[4]) {
    f32x4 oacc = {0.f, 0.f, 0.f, 0.f};
#pragma unroll
    for (int ks = 0; ks < 4; ++ks) {
      bf16x8 b = frag_row(svt_s[b2o], SVSTR, nt * 16, ks * 32, lane);
      oacc = MFMA(afp[ks], b, oacc, 0, 0, 0);
    }
    {
      float4 e4 = *(const float4*)&gc_all[no][it * 16 + r0];
      const float* ep = (const float*)&e4;
#pragma unroll
      for (int r = 0; r < 4; ++r) oacc[r] *= __expf(ep[r]) * SCALE;
    }
#pragma unroll
    for (int ks = 0; ks < 2; ++ks) {
      bf16x8 a = frag_row(sh_s[b2o], SHSTR, it * 16, ks * 32, lane);
      bf16x8 b = *(const bf16x8*)(vT_s[b3o] + vt_off(nt * 16 + jc, ks * 32 + (g4 << 3)));
      oacc = MFMA(a, b, oacc, 0, 0, 0);
    }
#pragma unroll
    for (int r = 0; r < 4; ++r) {
      int row = it * 16 + r0 + r;
      og[vbase + (size_t)(no * BT + row) * VD + nt * 16 + jc] = oacc[r];
    }
  };

  f32x4 Sa = {0.f, 0.f, 0.f, 0.f}, Sb = {0.f, 0.f, 0.f, 0.f};
  bf16x8 afp[4];

  loadpf(0);
#pragma unroll 1
  for (int i = 0; i < 8; ++i) {
    int cn = wave * 8 + i;
    float a = gg[gbase + cn * BT + lane];
#pragma unroll
    for (int off = 1; off < 64; off <<= 1) {
      float t = __shfl_up(a, off);
      if (lane >= off) a += t;
    }
    gc_all[cn][lane] = a;
    if (lane == 63) glast_all[cn] = a;
  }
  LGKM_BARRIER();
  stage(0, 0, 0);
  loadpf(1);
  LGKM_BARRIER();

  int b3 = 0;
#pragma unroll 1
  for (int n = 0; n < NCHUNK; ++n) {
    const int b2 = n & 1;
    const int b3n = (b3 == 2) ? 0 : b3 + 1;
    const int b3p = (b3 == 0) ? 2 : b3 - 1;

    if (n > 0) o_emit(n - 1, b2 ^ 1, b3p, afp);

    bf16x8 af[4];
#pragma unroll
    for (int ks = 0; ks < 4; ++ks)
      af[ks] = frag_row(q_s[b2], QSTR, it * 16, ks * 32, lane);

    f32x4 sa0 = {0.f,0.f,0.f,0.f}, sa1 = {0.f,0.f,0.f,0.f};
#pragma unroll
    for (int ks = 0; ks < 4; ++ks) {
      bf16x8 a0 = krow_frag(k_s[b2], jt0 * 16, ks * 32, lane);
      bf16x8 a1 = krow_frag(k_s[b2], (jt0 + 1) * 16, ks * 32, lane);
      sa0 = MFMA(a0, af[ks], sa0, 0, 0, 0);
      sa1 = MFMA(a1, af[ks], sa1, 0, 0, 0);
    }
    {
      int i0 = it * 16 + jc;
      float gci = gc_all[n][i0];
#pragma unroll
      for (int t = 0; t < 2; ++t) {
        f32x4 sv = t ? sa1 : sa0;
        int jb = (jt0 + t) * 16 + r0;
        float4 g4v = *(const float4*)&gc_all[n][jb];
        const float* gj = (const float*)&g4v;
        bf16x4 pk;
#pragma unroll
        for (int r = 0; r < 4; ++r) {
          float val = (i0 >= jb + r) ? sv[r] * __expf(gci - gj[r]) * SCALE : 0.f;
          pk[r] = (bf16)val;
        }
        *(bf16x4*)&sh_s[b2][i0 * SHSTR + jb] = pk;
      }
    }

    st4(&svt_s[b2][jc * SVSTR + wave * 16 + r0], Sa[0], Sa[1], Sa[2], Sa[3]);
    st4(&svt_s[b2][(16 + jc) * SVSTR + wave * 16 + r0], Sb[0], Sb[1], Sb[2], Sb[3]);
    {
      float dec = __expf(glast_all[n]);
#pragma unroll
      for (int r = 0; r < 4; ++r) { Sa[r] *= dec; Sb[r] *= dec; }
#pragma unroll
      for (int ks = 0; ks < 2; ++ks) {
        bf16x8 a = kcol_frag(k_s[b2], ks * 32 + (g4 << 3), wave * 16 + jc);
        bf16x8 b0 = *(const bf16x8*)(vwT_s[b3] + vt_off(jc, ks * 32 + (g4 << 3)));
        bf16x8 b1 = *(const bf16x8*)(vwT_s[b3] + vt_off(16 + jc, ks * 32 + (g4 << 3)));
        Sa = MFMA(a, b0, Sa, 0, 0, 0);
        Sb = MFMA(a, b1, Sb, 0, 0, 0);
      }
    }

    if (n + 1 < NCHUNK) {
      stage(b2 ^ 1, b3n, n + 1);
      if (n + 2 < NCHUNK) loadpf(n + 2);
    }

#pragma unroll
    for (int ks = 0; ks < 4; ++ks) afp[ks] = af[ks];
    b3 = b3n;

    LGKM_BARRIER();
  }

  o_emit(NCHUNK - 1, 1, 0, afp);
}

extern "C" void kernel_launch(void* const* d_in, const int* in_sizes, int n_in,
                              void* d_out, int out_size, void* d_ws, size_t ws_size,
                              hipStream_t stream) {
  const float* q = (const float*)d_in[0];
  const float* k = (const float*)d_in[1];
  const float* v = (const float*)d_in[2];
  const float* g = (const float*)d_in[3];
  float* o = (float*)d_out;
  if (ws_size >= WS_NEED) {
    float* ws = (float*)d_ws;
    gla_pre<<<dim3(192), dim3(512), 0, stream>>>(k, v, g, ws);
    gla_main<<<dim3(256), dim3(512), 0, stream>>>(q, k, v, g, o, ws);
  } else {
    gla_fused<<<dim3(256), dim3(512), 0, stream>>>(q, k, v, g, o);
  }
}